// Round 1
// 107.255 us; speedup vs baseline: 1.0505x; 1.0505x over previous
//
#include <hip/hip_runtime.h>
#include <hip/hip_bf16.h>
#include <math.h>

// Problem constants (from reference setup_inputs)
constexpr int B = 4, S = 10, N = 2048, D = 128;

constexpr int KS      = 8;            // database slices per (b,s,dir)
constexpr int SLICE   = N / KS;       // 256 db points per block
constexpr int QCHUNK  = 2;            // query chunks per (b,s,dir,slice)
constexpr int QPB     = N / QCHUNK;   // 1024 queries per block
constexpr int QPT     = 4;            // queries per thread
constexpr int THREADS = 256;
constexpr int CHAM_BLOCKS = B * S * 2 * KS * QCHUNK;   // 1280
constexpr int TOTQ    = B * S * 2 * N;        // 163840 (query, dir) pairs
constexpr int TEMP_ELEMS = B * (S - 1) * N;   // 73728
constexpr int TEMP_BLOCKS = 16;
constexpr int TEMP_PER_BLOCK = TEMP_ELEMS / TEMP_BLOCKS;  // 4608 = 18*256
constexpr int KL_ELEMS = B * S * D;           // 5120 = 20*256
constexpr int K2_BLOCKS = TOTQ / THREADS;     // 640

// ws layout (floats) — IDENTICAL to previous version:
//   [0 .. KS*TOTQ)                 partial d^2 per (slice, query)
//   [KS*TOTQ .. +K2_BLOCKS)        per-block chamfer distance sums (K2)
//   then TEMP_BLOCKS temporal partials, then 1 kl partial
constexpr size_t WS_PARTIAL = 0;
constexpr size_t WS_CHSUM   = (size_t)KS * TOTQ;
constexpr size_t WS_TPART   = WS_CHSUM + K2_BLOCKS;
constexpr size_t WS_KL      = WS_TPART + TEMP_BLOCKS;

typedef float v2f __attribute__((ext_vector_type(2)));

__device__ __forceinline__ v2f pk_fma(v2f a, v2f b, v2f c) {
    v2f d;
    asm("v_pk_fma_f32 %0, %1, %2, %3" : "=v"(d) : "v"(a), "v"(b), "v"(c));
    return d;
}

// valid result on thread 0 only
__device__ __forceinline__ float block_sum(float v, float* red) {
    #pragma unroll
    for (int off = 32; off > 0; off >>= 1)
        v += __shfl_down(v, off, 64);
    const int wid = threadIdx.x >> 6;
    if ((threadIdx.x & 63) == 0) red[wid] = v;
    __syncthreads();
    return red[0] + red[1] + red[2] + red[3];
}

// ---------------------------------------------------------------------------
// K1: blocks [0,1280): chamfer partials; [1280,1296): temporal; 1296: kl
// ---------------------------------------------------------------------------
__global__ __launch_bounds__(256) void k1_kernel(
        const float* __restrict__ pred, const float* __restrict__ tgt,
        const float* __restrict__ prior_mean, const float* __restrict__ prior_lv,
        const float* __restrict__ post_mean,  const float* __restrict__ post_lv,
        float* __restrict__ ws) {
    // pair-interleaved db: [2p]={x0,x1,y0,y1} [2p+1]={z0,z1,m0,m1}; +2 pad for prefetch
    __shared__ float4 db[SLICE + 2];
    __shared__ float red[4];

    const int bid = blockIdx.x;
    const int tid = threadIdx.x;

    if (bid < CHAM_BLOCKS) {
        const int ks  = bid & (KS - 1);
        const int dir = (bid >> 3) & 1;
        const int qc  = (bid >> 4) & 1;
        const int bs  = bid >> 5;                 // b*S + s  (0..39)
        const float* qb  = (dir ? tgt : pred) + (size_t)bs * N * 3;  // queries
        const float* dbp = (dir ? pred : tgt) + (size_t)bs * N * 3;  // database

        // stage 256 db points, pair-interleaved, m = -0.5*|g|^2
        if (tid < SLICE / 2) {
            const int p0 = ks * SLICE + 2 * tid;
            const float2* dp2 = (const float2*)(dbp + 3 * p0);  // 24B-aligned
            const float2 a = dp2[0], b2 = dp2[1], c = dp2[2];
            const float x0 = a.x, y0 = a.y, z0 = b2.x;
            const float x1 = b2.y, y1 = c.x, z1 = c.y;
            db[2 * tid + 0] = make_float4(x0, x1, y0, y1);
            db[2 * tid + 1] = make_float4(z0, z1,
                                          -0.5f * (x0 * x0 + y0 * y0 + z0 * z0),
                                          -0.5f * (x1 * x1 + y1 * y1 + z1 * z1));
        }

        // load 4 queries into registers (splatted for packed fma)
        v2f px2[QPT], py2[QPT], pz2[QPT];
        float pn[QPT], acc[QPT];
        #pragma unroll
        for (int i = 0; i < QPT; ++i) {
            const int q = qc * QPB + tid + THREADS * i;
            const float x = qb[3 * q + 0], y = qb[3 * q + 1], z = qb[3 * q + 2];
            px2[i] = (v2f){x, x};
            py2[i] = (v2f){y, y};
            pz2[i] = (v2f){z, z};
            pn[i]  = x * x + y * y + z * z;
            acc[i] = -1e30f;
        }
        __syncthreads();

        // max over slice of score = p.g - 0.5|g|^2 (2 db points per packed op)
        // software-pipelined: prefetch next iteration's LDS pair while computing
        float4 cA = db[0], cB = db[1];
        #pragma unroll 2
        for (int p = 0; p < SLICE / 2; ++p) {
            const float4 nA = db[2 * p + 2];   // last iter reads pad (unused)
            const float4 nB = db[2 * p + 3];
            const v2f x01 = (v2f){cA.x, cA.y};
            const v2f y01 = (v2f){cA.z, cA.w};
            const v2f z01 = (v2f){cB.x, cB.y};
            const v2f m01 = (v2f){cB.z, cB.w};
            #pragma unroll
            for (int i = 0; i < QPT; ++i) {
                v2f t = pk_fma(pz2[i], z01, m01);
                t = pk_fma(py2[i], y01, t);
                t = pk_fma(px2[i], x01, t);
                acc[i] = fmaxf(acc[i], fmaxf(t.x, t.y));   // v_max3_f32
            }
            cA = nA; cB = nB;
        }

        // partial d^2 for this slice (same values & addresses as before)
        float* part = ws + WS_PARTIAL + (size_t)ks * TOTQ
                    + (size_t)(bs * 2 + dir) * N + (size_t)qc * QPB;
        #pragma unroll
        for (int i = 0; i < QPT; ++i)
            part[tid + THREADS * i] = pn[i] - 2.0f * acc[i];
    } else if (bid < CHAM_BLOCKS + TEMP_BLOCKS) {
        // temporal: sum ||pred[:,s+1]-pred[:,s]||
        const int tb = bid - CHAM_BLOCKS;
        float s = 0.0f;
        for (int it = 0; it < TEMP_PER_BLOCK / THREADS; ++it) {
            const int i = tb * TEMP_PER_BLOCK + it * THREADS + tid;
            const int b = i / ((S - 1) * N);
            const int r = i % ((S - 1) * N);
            const float* p0 = pred + (size_t)(b * S * N + r) * 3;
            const float* p1 = p0 + (size_t)N * 3;
            const float dx = p1[0] - p0[0];
            const float dy = p1[1] - p0[1];
            const float dz = p1[2] - p0[2];
            s += sqrtf(dx * dx + dy * dy + dz * dz);
        }
        const float tot = block_sum(s, red);
        if (tid == 0) ws[WS_TPART + tb] = tot;
    } else {
        // kl term sum
        float s = 0.0f;
        for (int it = 0; it < KL_ELEMS / THREADS; ++it) {
            const int i = it * THREADS + tid;
            const float a  = prior_lv[i];
            const float bb = post_lv[i];
            const float dm = post_mean[i] - prior_mean[i];
            s += a - bb + (expf(bb) + dm * dm) * expf(-a) - 1.0f;
        }
        const float tot = block_sum(s, red);
        if (tid == 0) ws[WS_KL] = tot;
    }
}

// ---------------------------------------------------------------------------
// K2: per query min over KS slices, sqrt, per-block sum (640 blocks x 256)
// (unchanged — bit-identical reduction order)
// ---------------------------------------------------------------------------
__global__ __launch_bounds__(256) void k2_kernel(float* __restrict__ ws) {
    __shared__ float red[4];
    const int u = blockIdx.x * THREADS + threadIdx.x;   // < TOTQ
    const float* part = ws + WS_PARTIAL;
    float d2 = part[u];
    #pragma unroll
    for (int k = 1; k < KS; ++k)
        d2 = fminf(d2, part[(size_t)k * TOTQ + u]);
    const float d = sqrtf(fmaxf(d2, 0.0f));
    const float tot = block_sum(d, red);
    if (threadIdx.x == 0) ws[WS_CHSUM + blockIdx.x] = tot;
}

// ---------------------------------------------------------------------------
// K3: final combine (unchanged)
// ---------------------------------------------------------------------------
__global__ __launch_bounds__(256) void k3_kernel(const float* __restrict__ ws,
                                                 float* __restrict__ out) {
    __shared__ float red[4];
    float s = 0.0f;
    for (int i = threadIdx.x; i < K2_BLOCKS; i += THREADS)
        s += ws[WS_CHSUM + i];
    const float tot = block_sum(s, red);
    if (threadIdx.x == 0) {
        float tsum = 0.0f;
        for (int i = 0; i < TEMP_BLOCKS; ++i) tsum += ws[WS_TPART + i];
        const float recon    = tot / (float)(B * S * N);
        const float kl       = 0.5f * ws[WS_KL] / (float)(B * S);
        const float temporal = tsum / (float)TEMP_ELEMS;
        out[0] = recon + kl + 0.1f * temporal;
        out[1] = recon;
        out[2] = kl;
        out[3] = temporal;
        out[4] = 0.0f;
    }
}

extern "C" void kernel_launch(void* const* d_in, const int* in_sizes, int n_in,
                              void* d_out, int out_size, void* d_ws, size_t ws_size,
                              hipStream_t stream) {
    const float* pred = (const float*)d_in[0];
    const float* tgt  = (const float*)d_in[1];
    const float* pm   = (const float*)d_in[2];
    const float* plv  = (const float*)d_in[3];
    const float* qm   = (const float*)d_in[4];
    const float* qlv  = (const float*)d_in[5];
    float* out = (float*)d_out;
    float* ws  = (float*)d_ws;

    k1_kernel<<<CHAM_BLOCKS + TEMP_BLOCKS + 1, THREADS, 0, stream>>>(
        pred, tgt, pm, plv, qm, qlv, ws);
    k2_kernel<<<TOTQ / THREADS, THREADS, 0, stream>>>(ws);
    k3_kernel<<<1, THREADS, 0, stream>>>(ws, out);
}